// Round 5
// baseline (160.397 us; speedup 1.0000x reference)
//
#include <hip/hip_runtime.h>
#include <math.h>

#define HW     16384
#define NPIX   131072        // B*H*W
#define NPLANE 1310720       // B*C*H*W
#define TPB    64            // 1 wave per block
#define NBLK   512           // 512 waves total, 4 px/thread
#define BN_N   131072.0f
#define EPS_BN 1e-5f

typedef float v4 __attribute__((ext_vector_type(4)));

__device__ __forceinline__ float sigf(float x) { return 1.0f / (1.0f + __expf(-x)); }
__device__ __forceinline__ float tanh_fast(float x) {
    x = fminf(fmaxf(x, -15.0f), 15.0f);
    float e = __expf(2.0f * x);
    return (e - 1.0f) / (e + 1.0f);
}
__device__ __forceinline__ v4 sig4(v4 x) {
    v4 r; r.x = sigf(x.x); r.y = sigf(x.y); r.z = sigf(x.z); r.w = sigf(x.w); return r;
}
__device__ __forceinline__ v4 tanh4(v4 x) {
    v4 r; r.x = tanh_fast(x.x); r.y = tanh_fast(x.y); r.z = tanh_fast(x.z); r.w = tanh_fast(x.w); return r;
}
__device__ __forceinline__ v4 relu4(v4 x) {
    v4 r; r.x = fmaxf(x.x, 0.f); r.y = fmaxf(x.y, 0.f); r.z = fmaxf(x.z, 0.f); r.w = fmaxf(x.w, 0.f); return r;
}
__device__ __forceinline__ float hsum4(v4 a) { return (a.x + a.y) + (a.z + a.w); }
__device__ __forceinline__ float dot4(v4 a)  { return a.x * a.x + a.y * a.y + a.z * a.z + a.w * a.w; }
__device__ __forceinline__ float wred(float v) {
#pragma unroll
    for (int o = 32; o; o >>= 1) v += __shfl_down(v, o, 64);
    return v;
}
__device__ __forceinline__ v4 ld4(const float* p) { return *(const v4*)p; }
__device__ __forceinline__ void nt_st4(v4 v, float* p) {
    __builtin_nontemporal_store(v, (v4*)p);
}

// ---------------- K1: node0 (GRU0), comp_att, BN1 stats ----------------
__global__ __launch_bounds__(TPB, 1) void kernA(
    const float* __restrict__ f0, const float* __restrict__ f1,
    const float* __restrict__ h0, const float* __restrict__ h1, const float* __restrict__ h2,
    const float* __restrict__ W_att, const float* __restrict__ b_att,
    const float* __restrict__ W_r1,
    const float* __restrict__ Wg0, const float* __restrict__ bg0, const float* __restrict__ Wc0,
    float* __restrict__ node0, float* __restrict__ att_out, float* __restrict__ stats)
{
    __shared__ float sP[40];
    const int tid = threadIdx.x;
    const int g = blockIdx.x * TPB + tid;          // pixel-quad index
    const int b = g >> 12, sp = (g & 4095) << 2;
    const int base = b * (10 * HW) + sp;

    // hoist ALL global loads: 50 float4 = 200 VGPRs of data, 800 B/thread in flight
    v4 vh1[10], vh2[10], vf1[10], vf0[10], vh0[10];
#pragma unroll
    for (int c = 0; c < 10; c++) {
        vh1[c] = ld4(h1 + base + c * HW);
        vh2[c] = ld4(h2 + base + c * HW);
        vf1[c] = ld4(f1 + base + c * HW);
        vf0[c] = ld4(f0 + base + c * HW);
        vh0[c] = ld4(h0 + base + c * HW);
    }

    // comp_att
    v4 z = b_att[0];
#pragma unroll
    for (int c = 0; c < 10; c++) z += W_att[c] * vh1[c] + W_att[10 + c] * vh2[c];
    const v4 att = sig4(z);
    nt_st4(att, att_out + 4 * g);

    // x = [f1, (h1+h2)*att]; BN1 stats of y1 = W_r1 @ x
    v4 x[20];
#pragma unroll
    for (int c = 0; c < 10; c++) { x[c] = vf1[c]; x[10 + c] = (vh1[c] + vh2[c]) * att; }
#pragma unroll
    for (int o = 0; o < 20; o++) {
        v4 acc = 0.0f;
#pragma unroll
        for (int i = 0; i < 20; i++) acc += W_r1[o * 20 + i] * x[i];
        float s = wred(hsum4(acc));
        float q = wred(dot4(acc));
        if (tid == 0) { sP[o] = s; sP[20 + o] = q; }
    }

    // node0 = GRU0(x=h0, h=f0)
    v4 g0 = bg0[0], g1 = bg0[1];
#pragma unroll
    for (int i = 0; i < 10; i++) {
        g0 += Wg0[i] * vh0[i] + Wg0[10 + i] * vf0[i];
        g1 += Wg0[20 + i] * vh0[i] + Wg0[30 + i] * vf0[i];
    }
    const v4 r = sig4(g0), u = sig4(g1);
#pragma unroll
    for (int o = 0; o < 10; o++) {
        v4 acc = 0.0f;
#pragma unroll
        for (int i = 0; i < 10; i++)
            acc += Wc0[o * 20 + i] * vh0[i] + Wc0[o * 20 + 10 + i] * (r * vf0[i]);
        nt_st4((1.0f - u) * vf0[o] + u * tanh4(acc), node0 + base + o * HW);
    }

    __syncthreads();
    if (tid < 40) atomicAdd(&stats[tid], sP[tid]);   // 40 lanes -> 40 addrs, parallel
}

// ---------------- K2: recompute att+y1, BN1+ReLU, y2, BN2 stats ----------------
__global__ __launch_bounds__(TPB, 1) void kernC(
    const float* __restrict__ f1, const float* __restrict__ h1, const float* __restrict__ h2,
    const float* __restrict__ W_att, const float* __restrict__ b_att,
    const float* __restrict__ W_r1, const float* __restrict__ g_r1, const float* __restrict__ be_r1,
    const float* __restrict__ W_r2,
    float* __restrict__ stats, float* __restrict__ y2out)
{
    __shared__ float sP[20];
    const int tid = threadIdx.x;
    const int g = blockIdx.x * TPB + tid;
    const int b = g >> 12, sp = (g & 4095) << 2;
    const int base = b * (10 * HW) + sp;

    v4 vf1[10], vh1[10], vh2[10];
#pragma unroll
    for (int c = 0; c < 10; c++) {
        vh1[c] = ld4(h1 + base + c * HW);
        vh2[c] = ld4(h2 + base + c * HW);
        vf1[c] = ld4(f1 + base + c * HW);
    }

    v4 z = b_att[0];
#pragma unroll
    for (int c = 0; c < 10; c++) z += W_att[c] * vh1[c] + W_att[10 + c] * vh2[c];
    const v4 att = sig4(z);

    v4 x[20];
#pragma unroll
    for (int c = 0; c < 10; c++) { x[c] = vf1[c]; x[10 + c] = (vh1[c] + vh2[c]) * att; }

    v4 x2[20];
#pragma unroll
    for (int o = 0; o < 20; o++) {
        v4 acc = 0.0f;
#pragma unroll
        for (int i = 0; i < 20; i++) acc += W_r1[o * 20 + i] * x[i];
        const float mean = stats[o] * (1.0f / BN_N);
        const float var  = stats[20 + o] * (1.0f / BN_N) - mean * mean;
        const float a  = g_r1[o] * rsqrtf(var + EPS_BN);
        const float bb = be_r1[o] - mean * a;
        x2[o] = relu4(a * acc + bb);
    }

#pragma unroll
    for (int o = 0; o < 10; o++) {
        v4 acc = 0.0f;
#pragma unroll
        for (int i = 0; i < 20; i++) acc += W_r2[o * 20 + i] * x2[i];
        *(v4*)(y2out + base + o * HW) = acc;   // re-read by kernE: keep cacheable
        float s = wred(hsum4(acc));
        float q = wred(dot4(acc));
        if (tid == 0) { sP[o] = s; sP[10 + o] = q; }
    }
    __syncthreads();
    if (tid < 20) atomicAdd(&stats[40 + tid], sP[tid]);
}

// ---------------- K3: BN2, comp_full, node1 (GRU1) ----------------
__global__ __launch_bounds__(TPB, 1) void kernE(
    const float* __restrict__ f1, const float* __restrict__ y2in,
    const float* __restrict__ stats,
    const float* __restrict__ g_r2, const float* __restrict__ be_r2,
    const float* __restrict__ Wg1, const float* __restrict__ bg1, const float* __restrict__ Wc1,
    float* __restrict__ node1)
{
    const int tid = threadIdx.x;
    const int g = blockIdx.x * TPB + tid;
    const int b = g >> 12, sp = (g & 4095) << 2;
    const int base = b * (10 * HW) + sp;

    v4 vf1[10], vy2[10];
#pragma unroll
    for (int c = 0; c < 10; c++) {
        vf1[c] = ld4(f1 + base + c * HW);
        vy2[c] = ld4(y2in + base + c * HW);
    }

    v4 comp[10];
#pragma unroll
    for (int c = 0; c < 10; c++) {
        const float mean = stats[40 + c] * (1.0f / BN_N);
        const float var  = stats[50 + c] * (1.0f / BN_N) - mean * mean;
        const float a  = g_r2[c] * rsqrtf(var + EPS_BN);
        const float bb = be_r2[c] - mean * a;
        comp[c] = relu4(a * vy2[c] + bb);
    }

    v4 g0 = bg1[0], g1 = bg1[1];
#pragma unroll
    for (int i = 0; i < 10; i++) {
        g0 += Wg1[i] * comp[i] + Wg1[10 + i] * vf1[i];
        g1 += Wg1[20 + i] * comp[i] + Wg1[30 + i] * vf1[i];
    }
    const v4 r = sig4(g0), u = sig4(g1);
#pragma unroll
    for (int o = 0; o < 10; o++) {
        v4 acc = 0.0f;
#pragma unroll
        for (int i = 0; i < 10; i++)
            acc += Wc1[o * 20 + i] * comp[i] + Wc1[o * 20 + 10 + i] * (r * vf1[i]);
        nt_st4((1.0f - u) * vf1[o] + u * tanh4(acc), node1 + base + o * HW);
    }
}

extern "C" void kernel_launch(void* const* d_in, const int* in_sizes, int n_in,
                              void* d_out, int out_size, void* d_ws, size_t ws_size,
                              hipStream_t stream) {
    const float* f0    = (const float*)d_in[0];
    const float* f1    = (const float*)d_in[1];
    const float* h0    = (const float*)d_in[2];
    const float* h1    = (const float*)d_in[3];
    const float* h2    = (const float*)d_in[4];
    const float* W_att = (const float*)d_in[5];
    const float* b_att = (const float*)d_in[6];
    const float* W_r1  = (const float*)d_in[7];
    const float* g_r1  = (const float*)d_in[8];
    const float* be_r1 = (const float*)d_in[9];
    const float* W_r2  = (const float*)d_in[10];
    const float* g_r2  = (const float*)d_in[11];
    const float* be_r2 = (const float*)d_in[12];
    const float* Wg0   = (const float*)d_in[13];
    const float* bg0   = (const float*)d_in[14];
    const float* Wc0   = (const float*)d_in[15];
    const float* Wg1   = (const float*)d_in[16];
    const float* bg1   = (const float*)d_in[17];
    const float* Wc1   = (const float*)d_in[18];

    float* out   = (float*)d_out;
    float* node0 = out;
    float* node1 = out + NPLANE;
    float* attO  = out + 2 * NPLANE;

    float* stats = (float*)d_ws;            // 60 floats
    float* y2    = stats + 64;              // 10*NPIX floats

    hipMemsetAsync(stats, 0, 64 * sizeof(float), stream);

    dim3 grid(NBLK), blk(TPB);
    kernA<<<grid, blk, 0, stream>>>(f0, f1, h0, h1, h2, W_att, b_att, W_r1,
                                    Wg0, bg0, Wc0, node0, attO, stats);
    kernC<<<grid, blk, 0, stream>>>(f1, h1, h2, W_att, b_att, W_r1, g_r1, be_r1,
                                    W_r2, stats, y2);
    kernE<<<grid, blk, 0, stream>>>(f1, y2, stats, g_r2, be_r2, Wg1, bg1, Wc1,
                                    node1);
}